// Round 3
// baseline (470.379 us; speedup 1.0000x reference)
//
#include <hip/hip_runtime.h>
#include <math.h>

// WavelengthDependentPropagation: out = ifft2( fft2(x) * H(lam_c, fy, fx) )
// B=8, C=3, H=W=1024.  Transposed-spectrum pipeline: every pass row-oriented.
//   K0: build H table in T orientation: Htab[lam][kx][ky], pre-scaled by 2^-20
//   K1: fwd row FFT, store TRANSPOSED: T[x][y] = RowFFT(y)[x]
//   K2: per T-row (= original column): fwd FFT -> *H -> inv FFT, streaming,
//       wave-private, no block barriers
//   K3: transposed load (two 8-row phases per 128B line), inv row FFT -> planes

#define NIMG 24

static __device__ __forceinline__ void cmulf(float& ar, float& ai, float br, float bi) {
    float r = ar * br - ai * bi;
    float i = ar * bi + ai * br;
    ar = r; ai = i;
}
__device__ __forceinline__ float2 cadd(float2 a, float2 b){ return make_float2(a.x+b.x, a.y+b.y); }
__device__ __forceinline__ float2 csub(float2 a, float2 b){ return make_float2(a.x-b.x, a.y-b.y); }
__device__ __forceinline__ float2 cmul(float2 a, float c, float s){ return make_float2(a.x*c - a.y*s, a.x*s + a.y*c); }

// swizzled byte offset within an 8KB column buffer for complex index j
__device__ __forceinline__ int SW(int j) {
    int b = j << 3;
    return b ^ (((b >> 7) & 7) << 4);
}

// ---------------- transfer function (mirrors the jnp fp32 chain exactly) ----
__device__ __forceinline__ float2 computeH(float lam, int ky, int kx) {
    int iy = (ky < 512) ? ky : ky - 1024;
    int ix = (kx < 512) ? kx : kx - 1024;
    const double recip = 1.0 / (1024.0 * 8e-06);
    float fy = (float)((double)iy * recip);
    float fx = (float)((double)ix * recip);
    float f2  = __fadd_rn(__fmul_rn(fy, fy), __fmul_rn(fx, fx));
    float l2  = __fmul_rn(lam, lam);
    float arg = __fsub_rn(1.0f, __fmul_rn(l2, f2));
    float2 h = make_float2(0.0f, 0.0f);
    if (arg > 0.0f) {
        float t  = __fdiv_rn(6.28318530717958647692f, lam);
        t        = __fmul_rn(t, 0.05f);
        float kz = __fmul_rn(t, __fsqrt_rn(arg));
        double s, c;
        sincos((double)kz, &s, &c);
        const float sc = 9.5367431640625e-07f;              // 2^-20
        h = make_float2((float)c * sc, (float)s * sc);
    }
    return h;
}

// Htab[c][kx][ky]  (T orientation: contiguous in ky)
__global__ __launch_bounds__(256) void build_H_T(float2* __restrict__ Htab,
                                                 const float* __restrict__ wl) {
    int idx = blockIdx.x * 256 + threadIdx.x;
    int c   = idx >> 20;
    int rem = idx & 1048575;
    Htab[idx] = computeH(wl[c], rem & 1023, rem >> 10);
}

// ---------------- radix-4 butterflies ---------------------------------------
template<int SIGN>
__device__ __forceinline__ void dft4nt(float2& a0, float2& a1, float2& a2, float2& a3) {
    float2 t0 = cadd(a0, a2), t1 = csub(a0, a2);
    float2 t2 = cadd(a1, a3), t3 = csub(a1, a3);
    a0 = cadd(t0, t2);
    a2 = csub(t0, t2);
    a1 = make_float2(t1.x - SIGN * t3.y, t1.y + SIGN * t3.x);
    a3 = make_float2(t1.x + SIGN * t3.y, t1.y - SIGN * t3.x);
}
template<int SIGN>
__device__ __forceinline__ void dft4(float2& a0, float2& a1, float2& a2, float2& a3,
                                     float c1, float s1) {
    float c2 = c1*c1 - s1*s1, s2 = 2.f*c1*s1;
    float c3 = c2*c1 - s2*s1, s3 = s2*c1 + c2*s1;
    a1 = cmul(a1, c1, s1);
    a2 = cmul(a2, c2, s2);
    a3 = cmul(a3, c3, s3);
    dft4nt<SIGN>(a0, a1, a2, a3);
}

#define WSYNC() do { asm volatile("s_waitcnt lgkmcnt(0)" ::: "memory"); \
                     __builtin_amdgcn_wave_barrier(); } while (0)

// ---------------- 1024-pt wave-private FFT over swizzled 8KB LDS column -----
// 64 lanes x 16 complex.  Stages (0+1) regs -> LDS -> (2+3) regs -> LDS -> (4).
// Verified in R1/R2 (passing).  SIGN=-1 fwd, +1 inv (unnormalized).
template<int SIGN>
__device__ __forceinline__ void wave_fft(char* cb, int l) {
    const float SPI8   = SIGN * 0.39269908169872415481f;   // pi/8
    const float SPI32  = SIGN * 0.09817477042468103870f;   // pi/32
    const float SPI128 = SIGN * 0.02454369260617025967f;   // pi/128
    const float SPI512 = SIGN * 0.00613592315154256492f;   // pi/512
    const int swzE = (((l >> 4)    ) & 7) << 4;
    const int swzO = (((l >> 4) + 4) & 7) << 4;
    char* rbE = cb + ((8 * l) ^ swzE);
    char* rbO = cb + ((8 * l) ^ swzO);
    float2 v[4][4];

    // ---- Round A: stages 0 (j=l+64k) + 1 (j'=4l+q) -------------------------
    #pragma unroll
    for (int k = 0; k < 4; ++k) {
        #pragma unroll
        for (int r = 0; r < 4; ++r) {
            const int tt = k + 4 * r;
            v[k][r] = *(const float2*)(((tt & 1) ? rbO : rbE) + 512 * tt);
        }
    }
    #pragma unroll
    for (int k = 0; k < 4; ++k) dft4nt<SIGN>(v[k][0], v[k][1], v[k][2], v[k][3]);
    dft4nt<SIGN>(v[0][0], v[1][0], v[2][0], v[3][0]);
    #pragma unroll
    for (int q = 1; q < 4; ++q) {
        float s1, c1; __sincosf((float)q * SPI8, &s1, &c1);
        dft4<SIGN>(v[0][q], v[1][q], v[2][q], v[3][q], c1, s1);
    }
    {
        char* wb = cb + 128 * l;
        const int L7 = l & 7;
        #pragma unroll
        for (int p = 0; p < 4; ++p) {
            *(float4*)(wb + 16 * ((2*p+0) ^ L7)) =
                make_float4(v[p][0].x, v[p][0].y, v[p][1].x, v[p][1].y);
            *(float4*)(wb + 16 * ((2*p+1) ^ L7)) =
                make_float4(v[p][2].x, v[p][2].y, v[p][3].x, v[p][3].y);
        }
    }
    WSYNC();

    // ---- Round B: stages 2 (j=l+64k) + 3 (j'=64(l>>4)+(l&15)+16q) ----------
    #pragma unroll
    for (int k = 0; k < 4; ++k) {
        #pragma unroll
        for (int r = 0; r < 4; ++r) {
            const int tt = k + 4 * r;
            v[k][r] = *(const float2*)(((tt & 1) ? rbO : rbE) + 512 * tt);
        }
    }
    {
        const int jm2 = l & 15;
        float s1, c1; __sincosf((float)jm2 * SPI32, &s1, &c1);
        #pragma unroll
        for (int k = 0; k < 4; ++k) dft4<SIGN>(v[k][0], v[k][1], v[k][2], v[k][3], c1, s1);
        const int lo8 = 8 * (l & 15);
        const int hi  = 2048 * (l >> 4);
        #pragma unroll
        for (int q = 0; q < 4; ++q) {
            float s1b, c1b; __sincosf((float)(jm2 + 16 * q) * SPI128, &s1b, &c1b);
            dft4<SIGN>(v[0][q], v[1][q], v[2][q], v[3][q], c1b, s1b);
            #pragma unroll
            for (int p = 0; p < 4; ++p) {
                const int K = ((q + 4 * p) & 7) << 4;
                *(float2*)(cb + (lo8 ^ K) + hi + 128 * q + 512 * p) = v[p][q];
            }
        }
    }
    WSYNC();

    // ---- Round C: stage 4 (j''=l+64m), in-place on {l+64m+256q} ------------
    #pragma unroll
    for (int m = 0; m < 4; ++m) {
        #pragma unroll
        for (int r = 0; r < 4; ++r) {
            const int tt = m + 4 * r;
            v[m][r] = *(const float2*)(((tt & 1) ? rbO : rbE) + 512 * tt);
        }
    }
    #pragma unroll
    for (int m = 0; m < 4; ++m) {
        float s1, c1; __sincosf((float)(l + 64 * m) * SPI512, &s1, &c1);
        dft4<SIGN>(v[m][0], v[m][1], v[m][2], v[m][3], c1, s1);
        #pragma unroll
        for (int q = 0; q < 4; ++q) {
            const int tt = m + 4 * q;
            *(float2*)(((tt & 1) ? rbO : rbE) + 512 * tt) = v[m][q];
        }
    }
}

// ---------------- K1: fwd row FFT + transposed store -------------------------
// 512 thr = 8 waves, 8 rows/block, 64KB LDS.  Wave w FFTs row y0+w privately.
__global__ __launch_bounds__(512, 4) void k1_rows_T(const float* __restrict__ xr,
                                                    const float* __restrict__ xi,
                                                    float2* __restrict__ T) {
    __shared__ float4 ldsb[4096];
    char* lds = (char*)ldsb;
    const int t = threadIdx.x, w = t >> 6, l = t & 63;
    const int img = blockIdx.x >> 7;
    const int y0  = (blockIdx.x & 127) << 3;
    const long long ib = (long long)img << 20;
    char* cb = lds + 8192 * w;

    // coalesced load of row y0+w (both planes), interleave into private cb
    {
        const float4* rr = (const float4*)(xr + ib + (long long)(y0 + w) * 1024);
        const float4* ri = (const float4*)(xi + ib + (long long)(y0 + w) * 1024);
        const int swz = ((l >> 2) & 7) << 4;
        #pragma unroll
        for (int k = 0; k < 4; ++k) {
            float4 a = rr[64 * k + l], b = ri[64 * k + l];
            *(float4*)(cb + 2048 * k + ((32 * l) ^ swz))      = make_float4(a.x, b.x, a.y, b.y);
            *(float4*)(cb + 2048 * k + ((32 * l + 16) ^ swz)) = make_float4(a.z, b.z, a.w, b.w);
        }
    }
    WSYNC();
    wave_fft<-1>(cb, l);
    __syncthreads();

    // transposed store: T[x][y0 + 2seg..2seg+1], 64B segments (full lines)
    {
        const int seg = t & 3;
        const int xb  = t >> 2;                  // 0..127
        #pragma unroll
        for (int k = 0; k < 8; ++k) {
            int x = xb + 128 * k;
            float2 v0 = *(const float2*)(lds + 8192 * (2 * seg)     + SW(x));
            float2 v1 = *(const float2*)(lds + 8192 * (2 * seg + 1) + SW(x));
            *(float4*)(T + ib + (long long)x * 1024 + y0 + 2 * seg) =
                make_float4(v0.x, v0.y, v1.x, v1.y);
        }
    }
}

// ---------------- K2: column pass as streaming row pass on T -----------------
// 256 thr = 4 waves, one T-row (= one original column) per wave.  32KB LDS,
// no block barriers, 5 blocks/CU.
__global__ __launch_bounds__(256, 4) void k2_cols_H(float2* __restrict__ T,
                                                    const float2* __restrict__ Htab,
                                                    const float* __restrict__ wl) {
    __shared__ float4 ldsb[2048];
    char* lds = (char*)ldsb;
    const int t = threadIdx.x, w = t >> 6, l = t & 63;
    const int img = blockIdx.x >> 8;
    const int x   = ((blockIdx.x & 255) << 2) + w;
    const int lamIdx = img % 3;
    char* cb = lds + 8192 * w;
    float2* row = T + ((long long)img << 20) + (long long)x * 1024;
    const int swz = ((l >> 3) & 7) << 4;

    #pragma unroll
    for (int k = 0; k < 8; ++k) {
        float4 g = ((const float4*)row)[64 * k + l];
        *(float4*)(cb + 1024 * k + ((16 * l) ^ swz)) = g;
    }
    WSYNC();
    wave_fft<-1>(cb, l);
    WSYNC();
    {
        const float2* hrow = Htab ? (Htab + ((long long)lamIdx << 20) + (long long)x * 1024)
                                  : nullptr;
        const float lam = Htab ? 0.0f : wl[lamIdx];
        #pragma unroll
        for (int k = 0; k < 8; ++k) {
            float4* p = (float4*)(cb + 1024 * k + ((16 * l) ^ swz));
            float4 a = *p;
            float4 h;
            if (hrow) {
                h = ((const float4*)hrow)[64 * k + l];
            } else {
                int m = 128 * k + 2 * l;
                float2 h0 = computeH(lam, m,     x);
                float2 h1 = computeH(lam, m + 1, x);
                h = make_float4(h0.x, h0.y, h1.x, h1.y);
            }
            *p = make_float4(a.x * h.x - a.y * h.y, a.x * h.y + a.y * h.x,
                             a.z * h.z - a.w * h.w, a.z * h.w + a.w * h.z);
        }
    }
    WSYNC();
    wave_fft<1>(cb, l);
    WSYNC();
    #pragma unroll
    for (int k = 0; k < 8; ++k) {
        float4 g = *(const float4*)(cb + 1024 * k + ((16 * l) ^ swz));
        ((float4*)row)[64 * k + l] = g;
    }
}

// ---------------- K3: transposed load + inv row FFT -> output planes ---------
// 512 thr = 8 waves, 16 rows/block in TWO 8-row phases (phase 0 pulls the
// 128B line, phase 1 hits L2 on the second half) -> exact read traffic.
__global__ __launch_bounds__(512, 4) void k3_irows_T(const float2* __restrict__ T,
                                                     float* __restrict__ outr,
                                                     float* __restrict__ outi) {
    __shared__ float4 ldsb[4096];
    char* lds = (char*)ldsb;
    const int t = threadIdx.x, w = t >> 6, l = t & 63;
    const int img = blockIdx.x >> 6;
    const int y0  = (blockIdx.x & 63) << 4;
    const long long ib = (long long)img << 20;
    char* cb = lds + 8192 * w;

    for (int p = 0; p < 2; ++p) {
        const int yb = y0 + 8 * p;
        // transposed load: T[x][yb + 2seg..2seg+1]
        {
            const int seg = t & 3;
            const int xb  = t >> 2;
            #pragma unroll
            for (int k = 0; k < 8; ++k) {
                int x = xb + 128 * k;
                float4 g = *(const float4*)(T + ib + (long long)x * 1024 + yb + 2 * seg);
                *(float2*)(lds + 8192 * (2 * seg)     + SW(x)) = make_float2(g.x, g.y);
                *(float2*)(lds + 8192 * (2 * seg + 1) + SW(x)) = make_float2(g.z, g.w);
            }
        }
        __syncthreads();
        wave_fft<1>(cb, l);
        WSYNC();
        // store row yb+w to real/imag planes, coalesced
        {
            float4* pr = (float4*)(outr + ib + (long long)(yb + w) * 1024);
            float4* pi = (float4*)(outi + ib + (long long)(yb + w) * 1024);
            const int swz = ((l >> 2) & 7) << 4;
            #pragma unroll
            for (int k = 0; k < 4; ++k) {
                float4 c0 = *(const float4*)(cb + 2048 * k + ((32 * l) ^ swz));
                float4 c1 = *(const float4*)(cb + 2048 * k + ((32 * l + 16) ^ swz));
                pr[64 * k + l] = make_float4(c0.x, c0.z, c1.x, c1.z);
                pi[64 * k + l] = make_float4(c0.y, c0.w, c1.y, c1.w);
            }
        }
        __syncthreads();
    }
}

// ---------------- launch ------------------------------------------------------
extern "C" void kernel_launch(void* const* d_in, const int* in_sizes, int n_in,
                              void* d_out, int out_size, void* d_ws, size_t ws_size,
                              hipStream_t stream) {
    const float* xr = (const float*)d_in[0];
    const float* xi = (const float*)d_in[1];
    const float* wl = (const float*)d_in[2];
    float* out = (float*)d_out;

    const size_t planeElems = (size_t)NIMG * 1024 * 1024;          // 24M
    float2* wsC = (float2*)d_ws;                                   // 192 MB
    const size_t needC = planeElems * sizeof(float2);
    const size_t needH = (size_t)3 * 1024 * 1024 * sizeof(float2); // 24 MB
    float2* Htab = nullptr;
    if (ws_size >= needC + needH) {
        Htab = (float2*)((char*)d_ws + needC);
        build_H_T<<<12288, 256, 0, stream>>>(Htab, wl);
    }
    k1_rows_T<<<NIMG * 128, 512, 0, stream>>>(xr, xi, wsC);
    k2_cols_H<<<NIMG * 256, 256, 0, stream>>>(wsC, Htab, wl);
    k3_irows_T<<<NIMG * 64, 512, 0, stream>>>(wsC, out, out + planeElems);
}

// Round 4
// 284.814 us; speedup vs baseline: 1.6515x; 1.6515x over previous
//
#include <hip/hip_runtime.h>
#include <math.h>

// WavelengthDependentPropagation: out = ifft2( fft2(x) * H(lam_c, fy, fx) )
// B=8, C=3, H=W=1024.  Panel-layout pipeline: every global access line-exact.
//   ws layout: [img:24][xt:128][y:1024][xi:8] complex  (panel = 64KB contiguous)
//   K0: build H table in panel layout, pre-scaled by 2^-20
//   K1: fwd row FFT (8 rows/block, wave-private) -> panel-store
//   K2: per panel: fwd col FFT -> *H -> inv col FFT (contiguous 64KB I/O)
//   K3: panel-gather -> inv row FFT -> output planes

#define NIMG 24

__device__ __forceinline__ float2 cadd(float2 a, float2 b){ return make_float2(a.x+b.x, a.y+b.y); }
__device__ __forceinline__ float2 csub(float2 a, float2 b){ return make_float2(a.x-b.x, a.y-b.y); }
__device__ __forceinline__ float2 cmul(float2 a, float c, float s){ return make_float2(a.x*c - a.y*s, a.x*s + a.y*c); }

// swizzled byte offset within an 8KB column buffer for complex index j
__device__ __forceinline__ int SW(int j) {
    int b = j << 3;
    return b ^ (((b >> 7) & 7) << 4);
}
// same swizzle for an aligned complex PAIR (16B unit), a = j>>1
__device__ __forceinline__ int SW16(int a) {
    int b = a << 4;
    return b ^ (((b >> 7) & 7) << 4);
}

// ---------------- transfer function (mirrors the jnp fp32 chain exactly) ----
__device__ __forceinline__ float2 computeH(float lam, int ky, int kx) {
    int iy = (ky < 512) ? ky : ky - 1024;
    int ix = (kx < 512) ? kx : kx - 1024;
    const double recip = 1.0 / (1024.0 * 8e-06);
    float fy = (float)((double)iy * recip);
    float fx = (float)((double)ix * recip);
    float f2  = __fadd_rn(__fmul_rn(fy, fy), __fmul_rn(fx, fx));
    float l2  = __fmul_rn(lam, lam);
    float arg = __fsub_rn(1.0f, __fmul_rn(l2, f2));
    float2 h = make_float2(0.0f, 0.0f);
    if (arg > 0.0f) {
        float t  = __fdiv_rn(6.28318530717958647692f, lam);
        t        = __fmul_rn(t, 0.05f);
        float kz = __fmul_rn(t, __fsqrt_rn(arg));
        double s, c;
        sincos((double)kz, &s, &c);
        const float sc = 9.5367431640625e-07f;              // 2^-20
        h = make_float2((float)c * sc, (float)s * sc);
    }
    return h;
}

// Htab[c][xt][y][xi]  (panel orientation, matches ws)
__global__ __launch_bounds__(256) void build_H_P(float2* __restrict__ Htab,
                                                 const float* __restrict__ wl) {
    int idx = blockIdx.x * 256 + threadIdx.x;
    int c   = idx >> 20;
    int rem = idx & 1048575;
    int xt  = rem >> 13;
    int y   = (rem >> 3) & 1023;
    int xi  = rem & 7;
    Htab[idx] = computeH(wl[c], y, (xt << 3) | xi);
}

// ---------------- radix-4 butterflies ---------------------------------------
template<int SIGN>
__device__ __forceinline__ void dft4nt(float2& a0, float2& a1, float2& a2, float2& a3) {
    float2 t0 = cadd(a0, a2), t1 = csub(a0, a2);
    float2 t2 = cadd(a1, a3), t3 = csub(a1, a3);
    a0 = cadd(t0, t2);
    a2 = csub(t0, t2);
    a1 = make_float2(t1.x - SIGN * t3.y, t1.y + SIGN * t3.x);
    a3 = make_float2(t1.x + SIGN * t3.y, t1.y - SIGN * t3.x);
}
template<int SIGN>
__device__ __forceinline__ void dft4(float2& a0, float2& a1, float2& a2, float2& a3,
                                     float c1, float s1) {
    float c2 = c1*c1 - s1*s1, s2 = 2.f*c1*s1;
    float c3 = c2*c1 - s2*s1, s3 = s2*c1 + c2*s1;
    a1 = cmul(a1, c1, s1);
    a2 = cmul(a2, c2, s2);
    a3 = cmul(a3, c3, s3);
    dft4nt<SIGN>(a0, a1, a2, a3);
}

#define WSYNC() do { asm volatile("s_waitcnt lgkmcnt(0)" ::: "memory"); \
                     __builtin_amdgcn_wave_barrier(); } while (0)

// ---------------- 1024-pt wave-private FFT over swizzled 8KB LDS column -----
// 64 lanes x 16 complex.  Verified R1-R3.  SIGN=-1 fwd, +1 inv (unnormalized).
template<int SIGN>
__device__ __forceinline__ void wave_fft(char* cb, int l) {
    const float SPI8   = SIGN * 0.39269908169872415481f;   // pi/8
    const float SPI32  = SIGN * 0.09817477042468103870f;   // pi/32
    const float SPI128 = SIGN * 0.02454369260617025967f;   // pi/128
    const float SPI512 = SIGN * 0.00613592315154256492f;   // pi/512
    const int swzE = (((l >> 4)    ) & 7) << 4;
    const int swzO = (((l >> 4) + 4) & 7) << 4;
    char* rbE = cb + ((8 * l) ^ swzE);
    char* rbO = cb + ((8 * l) ^ swzO);
    float2 v[4][4];

    // ---- Round A: stages 0 (j=l+64k) + 1 (j'=4l+q) -------------------------
    #pragma unroll
    for (int k = 0; k < 4; ++k) {
        #pragma unroll
        for (int r = 0; r < 4; ++r) {
            const int tt = k + 4 * r;
            v[k][r] = *(const float2*)(((tt & 1) ? rbO : rbE) + 512 * tt);
        }
    }
    #pragma unroll
    for (int k = 0; k < 4; ++k) dft4nt<SIGN>(v[k][0], v[k][1], v[k][2], v[k][3]);
    dft4nt<SIGN>(v[0][0], v[1][0], v[2][0], v[3][0]);
    #pragma unroll
    for (int q = 1; q < 4; ++q) {
        float s1, c1; __sincosf((float)q * SPI8, &s1, &c1);
        dft4<SIGN>(v[0][q], v[1][q], v[2][q], v[3][q], c1, s1);
    }
    {
        char* wb = cb + 128 * l;
        const int L7 = l & 7;
        #pragma unroll
        for (int p = 0; p < 4; ++p) {
            *(float4*)(wb + 16 * ((2*p+0) ^ L7)) =
                make_float4(v[p][0].x, v[p][0].y, v[p][1].x, v[p][1].y);
            *(float4*)(wb + 16 * ((2*p+1) ^ L7)) =
                make_float4(v[p][2].x, v[p][2].y, v[p][3].x, v[p][3].y);
        }
    }
    WSYNC();

    // ---- Round B: stages 2 (j=l+64k) + 3 (j'=64(l>>4)+(l&15)+16q) ----------
    #pragma unroll
    for (int k = 0; k < 4; ++k) {
        #pragma unroll
        for (int r = 0; r < 4; ++r) {
            const int tt = k + 4 * r;
            v[k][r] = *(const float2*)(((tt & 1) ? rbO : rbE) + 512 * tt);
        }
    }
    {
        const int jm2 = l & 15;
        float s1, c1; __sincosf((float)jm2 * SPI32, &s1, &c1);
        #pragma unroll
        for (int k = 0; k < 4; ++k) dft4<SIGN>(v[k][0], v[k][1], v[k][2], v[k][3], c1, s1);
        const int lo8 = 8 * (l & 15);
        const int hi  = 2048 * (l >> 4);
        #pragma unroll
        for (int q = 0; q < 4; ++q) {
            float s1b, c1b; __sincosf((float)(jm2 + 16 * q) * SPI128, &s1b, &c1b);
            dft4<SIGN>(v[0][q], v[1][q], v[2][q], v[3][q], c1b, s1b);
            #pragma unroll
            for (int p = 0; p < 4; ++p) {
                const int K = ((q + 4 * p) & 7) << 4;
                *(float2*)(cb + (lo8 ^ K) + hi + 128 * q + 512 * p) = v[p][q];
            }
        }
    }
    WSYNC();

    // ---- Round C: stage 4 (j''=l+64m), in-place on {l+64m+256q} ------------
    #pragma unroll
    for (int m = 0; m < 4; ++m) {
        #pragma unroll
        for (int r = 0; r < 4; ++r) {
            const int tt = m + 4 * r;
            v[m][r] = *(const float2*)(((tt & 1) ? rbO : rbE) + 512 * tt);
        }
    }
    #pragma unroll
    for (int m = 0; m < 4; ++m) {
        float s1, c1; __sincosf((float)(l + 64 * m) * SPI512, &s1, &c1);
        dft4<SIGN>(v[m][0], v[m][1], v[m][2], v[m][3], c1, s1);
        #pragma unroll
        for (int q = 0; q < 4; ++q) {
            const int tt = m + 4 * q;
            *(float2*)(((tt & 1) ? rbO : rbE) + 512 * tt) = v[m][q];
        }
    }
}

// ---------------- K1: fwd row FFT + panel store ------------------------------
// 512 thr = 8 waves, 8 rows/block, 64KB LDS.  Wave w FFTs row y0+w privately.
__global__ __launch_bounds__(512, 4) void k1_rows_P(const float* __restrict__ xr,
                                                    const float* __restrict__ xi,
                                                    float2* __restrict__ ws) {
    __shared__ float4 ldsb[4096];
    char* lds = (char*)ldsb;
    const int t = threadIdx.x, w = t >> 6, l = t & 63;
    const int img = blockIdx.x >> 7;
    const int y0  = (blockIdx.x & 127) << 3;
    const long long ib = (long long)img << 20;
    char* cb = lds + 8192 * w;

    // coalesced load of row y0+w (both planes), interleave into private cb
    {
        const float4* rr = (const float4*)(xr + ib + (long long)(y0 + w) * 1024);
        const float4* ri = (const float4*)(xi + ib + (long long)(y0 + w) * 1024);
        const int swz = ((l >> 2) & 7) << 4;
        #pragma unroll
        for (int k = 0; k < 4; ++k) {
            float4 a = rr[64 * k + l], b = ri[64 * k + l];
            *(float4*)(cb + 2048 * k + ((32 * l) ^ swz))      = make_float4(a.x, b.x, a.y, b.y);
            *(float4*)(cb + 2048 * k + ((32 * l + 16) ^ swz)) = make_float4(a.z, b.z, a.w, b.w);
        }
    }
    WSYNC();
    wave_fft<-1>(cb, l);
    __syncthreads();

    // panel store: thread t, iter k: row y0+k, columns x = (t>>2)*8 + 2(t&3) (+1)
    {
        const int xt = t >> 2, c2 = t & 3;
        const int a  = xt * 4 + c2;              // complex-pair index in row
        #pragma unroll
        for (int k = 0; k < 8; ++k) {
            float4 vv = *(const float4*)(lds + 8192 * k + SW16(a));
            *(float4*)(ws + ib + (long long)xt * 8192 + (y0 + k) * 8 + 2 * c2) = vv;
        }
    }
}

// ---------------- K2: column FFT * H * inverse, contiguous panel I/O ---------
// 512 thr = 8 waves, one 8-column panel (64KB) per block, in place.
__global__ __launch_bounds__(512, 4) void k2_cols_H(float2* __restrict__ ws,
                                                    const float2* __restrict__ Htab,
                                                    const float* __restrict__ wl) {
    __shared__ float4 ldsb[4096];
    char* lds = (char*)ldsb;
    const int t   = threadIdx.x;
    const int img = blockIdx.x >> 7;
    const int xt  = blockIdx.x & 127;
    const int lamIdx = img % 3;
    float2* panel = ws + ((long long)img << 20) + (long long)xt * 8192;

    // I/O mapping: float4 index 512k+t -> (y = 128k + (t>>2), xi = 2(t&3), +1)
    const int c2  = t & 3;
    const int row = t >> 2;                        // 0..127
    char* io0 = lds + 16384 * c2 + SW(row);        // col 2c2
    char* io1 = io0 + 8192;                        // col 2c2+1

    // --- load panel (fully contiguous 64KB) ---------------------------------
    #pragma unroll
    for (int k = 0; k < 8; ++k) {
        float4 g = ((const float4*)panel)[512 * k + t];
        *(float2*)(io0 + 1024 * k) = make_float2(g.x, g.y);
        *(float2*)(io1 + 1024 * k) = make_float2(g.z, g.w);
    }
    __syncthreads();

    // --- forward column FFT: wave w owns column w ---------------------------
    const int w = t >> 6, l = t & 63;
    char* cb = lds + 8192 * w;
    wave_fft<-1>(cb, l);
    __syncthreads();

    // --- multiply by H(lam, ky, kx) * 2^-20  (contiguous panel reads) -------
    {
        const float4* hp = Htab ? (const float4*)(Htab + (((long long)lamIdx) << 20)
                                                  + (long long)xt * 8192)
                                : nullptr;
        const float lam = Htab ? 0.0f : wl[lamIdx];
        #pragma unroll
        for (int k = 0; k < 8; ++k) {
            float4 h;
            if (hp) {
                h = hp[512 * k + t];
            } else {
                int ky = 128 * k + row;
                float2 h0 = computeH(lam, ky, xt * 8 + 2 * c2);
                float2 h1 = computeH(lam, ky, xt * 8 + 2 * c2 + 1);
                h = make_float4(h0.x, h0.y, h1.x, h1.y);
            }
            float2* p0 = (float2*)(io0 + 1024 * k);
            float2* p1 = (float2*)(io1 + 1024 * k);
            float2 a = *p0;
            *p0 = make_float2(a.x * h.x - a.y * h.y, a.x * h.y + a.y * h.x);
            float2 b = *p1;
            *p1 = make_float2(b.x * h.z - b.y * h.w, b.x * h.w + b.y * h.z);
        }
    }
    __syncthreads();

    // --- inverse column FFT -------------------------------------------------
    wave_fft<1>(cb, l);
    __syncthreads();

    // --- store panel back (fully contiguous) --------------------------------
    #pragma unroll
    for (int k = 0; k < 8; ++k) {
        float2 a = *(const float2*)(io0 + 1024 * k);
        float2 b = *(const float2*)(io1 + 1024 * k);
        ((float4*)panel)[512 * k + t] = make_float4(a.x, a.y, b.x, b.y);
    }
}

// ---------------- K3: panel gather + inv row FFT -> output planes ------------
// 512 thr = 8 waves, 8 rows/block (mirror of K1).
__global__ __launch_bounds__(512, 4) void k3_irows_P(const float2* __restrict__ ws,
                                                     float* __restrict__ outr,
                                                     float* __restrict__ outi) {
    __shared__ float4 ldsb[4096];
    char* lds = (char*)ldsb;
    const int t = threadIdx.x, w = t >> 6, l = t & 63;
    const int img = blockIdx.x >> 7;
    const int y0  = (blockIdx.x & 127) << 3;
    const long long ib = (long long)img << 20;
    char* cb = lds + 8192 * w;

    // panel gather: thread t, iter k: row y0+k, cols x = (t>>2)*8 + 2(t&3) (+1)
    {
        const int xt = t >> 2, c2 = t & 3;
        const int a  = xt * 4 + c2;
        #pragma unroll
        for (int k = 0; k < 8; ++k) {
            float4 g = *(const float4*)(ws + ib + (long long)xt * 8192 + (y0 + k) * 8 + 2 * c2);
            *(float4*)(lds + 8192 * k + SW16(a)) = g;
        }
    }
    __syncthreads();
    wave_fft<1>(cb, l);
    WSYNC();

    // store row y0+w to real/imag planes, coalesced
    {
        float4* pr = (float4*)(outr + ib + (long long)(y0 + w) * 1024);
        float4* pi = (float4*)(outi + ib + (long long)(y0 + w) * 1024);
        const int swz = ((l >> 2) & 7) << 4;
        #pragma unroll
        for (int k = 0; k < 4; ++k) {
            float4 c0 = *(const float4*)(cb + 2048 * k + ((32 * l) ^ swz));
            float4 c1 = *(const float4*)(cb + 2048 * k + ((32 * l + 16) ^ swz));
            pr[64 * k + l] = make_float4(c0.x, c0.z, c1.x, c1.z);
            pi[64 * k + l] = make_float4(c0.y, c0.w, c1.y, c1.w);
        }
    }
}

// ---------------- launch ------------------------------------------------------
extern "C" void kernel_launch(void* const* d_in, const int* in_sizes, int n_in,
                              void* d_out, int out_size, void* d_ws, size_t ws_size,
                              hipStream_t stream) {
    const float* xr = (const float*)d_in[0];
    const float* xi = (const float*)d_in[1];
    const float* wl = (const float*)d_in[2];
    float* out = (float*)d_out;

    const size_t planeElems = (size_t)NIMG * 1024 * 1024;          // 24M
    float2* wsC = (float2*)d_ws;                                   // 192 MB
    const size_t needC = planeElems * sizeof(float2);
    const size_t needH = (size_t)3 * 1024 * 1024 * sizeof(float2); // 24 MB
    float2* Htab = nullptr;
    if (ws_size >= needC + needH) {
        Htab = (float2*)((char*)d_ws + needC);
        build_H_P<<<12288, 256, 0, stream>>>(Htab, wl);
    }
    k1_rows_P<<<NIMG * 128, 512, 0, stream>>>(xr, xi, wsC);
    k2_cols_H<<<NIMG * 128, 512, 0, stream>>>(wsC, Htab, wl);
    k3_irows_P<<<NIMG * 128, 512, 0, stream>>>(wsC, out, out + planeElems);
}